// Round 10
// baseline (322.876 us; speedup 1.0000x reference)
//
#include <hip/hip_runtime.h>

typedef unsigned int u32;
typedef unsigned short u16;

#define NN 50000
#define EE 1250000
#define DD 128
#define HH 64
#define NCLS 10
#define NG 128
#define MAXDEG 80                    // Poisson(25): P(deg>=80) ~ 0

#define NTILES ((NN + 63) / 64)     // 782

#define PBUK 392                     // buckets = dst>>7
#define SBLK 256                     // sort chunks
#define CHUNK ((EE + SBLK - 1) / SBLK)  // 4883
#define NDP  (PBUK * 128)            // 50176
#define EPKB ((CHUNK * 4 + 15) & ~15)   // 19536 B LDS edge cache per psort chunk

// wtb layout (u16 units): layer hi [8][4096] | layer lo [8][4096] | e1 hi [64][128]
//                         | e1 lo | e2 hi [64][64] | e2 lo
#define WT_LO  (8 * 4096)            // 32768
#define WT_E1  (16 * 4096)           // 65536
#define WT_E1L (WT_E1 + 8192)        // 73728
#define WT_E2  (WT_E1 + 16384)       // 81920
#define WT_E2L (WT_E2 + 4096)        // 86016
#define WT_TOT (WT_E2 + 8192)        // 90112 u16 = 176 KB

// Round-2: int inputs are int32. ei int32 [2,E]: src=ei[e], dst=ei[EE+e].
// Round-3: no ReLU between GraphConv out and post-MLP.
// Round-7..10: adjacency via per-block counting sort (full-line writes only).
// Round-16: no coop grid.sync() on 8 non-coherent XCDs.
// Round-19: fp32 h dropped (bf16 shadow).
// Round-20: k_dense on MFMA bf16 16x16x32; weights hi/lo split.
// Round-21: embed GEMM on MFMA; k_wprep hoisted; sentinel-padded slots.
// Round-22: ILP lesson -- latency-bound gathers need max outstanding loads/wave.
// Round-24: psort-first + SBLK 256 (LDS 22.2KB).
// Round-25: k_adj hoisted descriptors + 4x16-lane segments (59.5 -> ~20us).
// Round-26: agg fused into dense REGRESSED (130us; gather-wave count matters). REVERTED.
// Round-27..28: h plane-split + 2-pass gather REGRESSED (+18us: slot indices
//   re-read 2x uncached via nontemporal; per-node lanes halved). REVERTED.
//   k_agg's half-wave/16-in-flight/one-pass form is settled (3 attempts lost).
// Round-29 (this): round-6 winner verbatim + k_cls fused into dense-L1 via
//   last-block pattern (validated in R26's kernel: ctr zeroed by k_adj,
//   pooled re-read with atomicAdd(p,0.0f) coherent reads). 8 -> 7 launches.

__device__ __forceinline__ u32 f2bf(float f) {           // RNE fp32->bf16
    u32 u = __float_as_uint(f);
    return (u + 0x7FFFu + ((u >> 16) & 1u)) >> 16;
}
__device__ __forceinline__ float bf2f(u16 v) {
    return __uint_as_float(((u32)v) << 16);
}

typedef __attribute__((ext_vector_type(8))) short bf16x8;   // 8 bf16 = 4 VGPR
typedef __attribute__((ext_vector_type(4))) float f32x4;

// ---------------- weight prep: transpose [k][n] -> [n][k], split bf16 hi/lo ----------------

__global__ __launch_bounds__(256) void k_wprep(
    const float* __restrict__ rel_w, const float* __restrict__ root_w,
    const float* __restrict__ pw1, const float* __restrict__ pw2,
    const float* __restrict__ ew1, const float* __restrict__ ew2,
    u16* __restrict__ wtb) {
    __shared__ float ldsf[128 * 65];                     // 33280 B (e1 worst case)
    const int t = threadIdx.x;
    const int m = blockIdx.x;                            // 0..7 layer mats, 8=e1, 9=e2
    if (m < 8) {
        const int layer = m >> 2, which = m & 3;
        const float* srcw =
            (which == 0 ? rel_w : which == 1 ? root_w : which == 2 ? pw1 : pw2)
            + (size_t)layer * HH * HH;
        #pragma unroll
        for (int r = 0; r < 16; ++r) {
            int idx = r * 256 + t;
            int k = idx >> 6, n = idx & 63;
            ldsf[k * 65 + n] = srcw[idx];                // coalesced read
        }
        __syncthreads();
        #pragma unroll
        for (int r = 0; r < 16; ++r) {
            int idx = r * 256 + t;
            int n = idx >> 6, k = idx & 63;
            float v = ldsf[k * 65 + n];                  // stride 65 -> conflict-free
            u16 hi = (u16)f2bf(v);
            u16 lo = (u16)f2bf(v - bf2f(hi));
            wtb[m * 4096 + idx] = hi;
            wtb[WT_LO + m * 4096 + idx] = lo;
        }
    } else if (m == 8) {                                 // emb_w1: [128][64] -> [64][128]
        #pragma unroll
        for (int r = 0; r < 32; ++r) {
            int idx = r * 256 + t;
            int k = idx >> 6, n = idx & 63;
            ldsf[k * 65 + n] = ew1[idx];
        }
        __syncthreads();
        #pragma unroll
        for (int r = 0; r < 32; ++r) {
            int idx = r * 256 + t;
            int n = idx >> 7, k = idx & 127;
            float v = ldsf[k * 65 + n];
            u16 hi = (u16)f2bf(v);
            u16 lo = (u16)f2bf(v - bf2f(hi));
            wtb[WT_E1 + idx] = hi;
            wtb[WT_E1L + idx] = lo;
        }
    } else {                                             // emb_w2: 64x64
        #pragma unroll
        for (int r = 0; r < 16; ++r) {
            int idx = r * 256 + t;
            int k = idx >> 6, n = idx & 63;
            ldsf[k * 65 + n] = ew2[idx];
        }
        __syncthreads();
        #pragma unroll
        for (int r = 0; r < 16; ++r) {
            int idx = r * 256 + t;
            int n = idx >> 6, k = idx & 63;
            float v = ldsf[k * 65 + n];
            u16 hi = (u16)f2bf(v);
            u16 lo = (u16)f2bf(v - bf2f(hi));
            wtb[WT_E2 + idx] = hi;
            wtb[WT_E2L + idx] = lo;
        }
    }
}

// ---------------- merged launch 1: psort chunks FIRST, then embed tiles (MFMA) ----------------
// Frag layouts (mfma_f32_16x16x32_bf16, verified):
//   A: lane l -> row l&15,  k = 8*(l>>4)+j (16B contiguous)
//   B: lane l -> col l&15,  k = 8*(l>>4)+j   (weights pre-transposed [n][k])
//   C: lane l -> col l&15,  row = 4*(l>>4)+r
// x and h1 split hi/lo bf16 -> embed is exact to ~2^-17.

__global__ __launch_bounds__(256) void k_embed_psort(
    const float* __restrict__ x,
    const float* __restrict__ b1, const float* __restrict__ b2,
    const u16* __restrict__ wtb,
    u16* __restrict__ hb,
    const int* __restrict__ ei, u32* __restrict__ bedges,
    int* __restrict__ gboff, int* __restrict__ ghist) {
    __shared__ __align__(16) char smem[EPKB + PBUK * 8 + 32];   // 22.2 KB
    const int t = threadIdx.x;

    if (blockIdx.x < SBLK) {
        // ---- psort chunk (long pole: starts at t=0 on every CU) ----
        u32* epk   = (u32*)smem;                 // packed edge cache [CHUNK]
        int* hist  = (int*)(smem + EPKB);
        int* boffS = hist + PBUK;
        int* wsum  = boffS + PBUK;
        const int cb = blockIdx.x;
        const int base = cb * CHUNK;
        const int n = min(CHUNK, EE - base);

        for (int b = t; b < PBUK; b += 256) hist[b] = 0;
        __syncthreads();
        // pass 1: pack edges into LDS + histogram (ILP-8 strided loads)
        for (int i0 = t; i0 < n; i0 += 2048) {
            int sV[8], dV[8];
            #pragma unroll
            for (int j = 0; j < 8; ++j) {
                int i = i0 + j * 256;
                sV[j] = -1; dV[j] = -1;
                if (i < n) { sV[j] = ei[base + i]; dV[j] = ei[EE + base + i]; }
            }
            #pragma unroll
            for (int j = 0; j < 8; ++j) {
                int i = i0 + j * 256;
                if (i < n) {
                    bool ok = (unsigned)sV[j] < NN && (unsigned)dV[j] < NN;
                    u32 w = ok ? (((u32)(dV[j] >> 7) << 23) | ((u32)sV[j] << 7) | (u32)(dV[j] & 127))
                               : 0xFFFFFFFFu;
                    epk[i] = w;
                    if (ok) atomicAdd(&hist[dV[j] >> 7], 1);
                }
            }
        }
        __syncthreads();
        int v = 0, h0 = 0;
        if (t < PBUK / 2) { h0 = hist[2 * t]; v = h0 + hist[2 * t + 1]; }
        int lane = t & 63, wd = t >> 6;
        int incl = v;
        #pragma unroll
        for (int d = 1; d < 64; d <<= 1) {
            int tt = __shfl_up(incl, d);
            if (lane >= d) incl += tt;
        }
        if (lane == 63) wsum[wd] = incl;
        __syncthreads();
        int woff = 0;
        for (int w = 0; w < wd; ++w) woff += wsum[w];
        if (t < PBUK / 2) {
            int excl = woff + incl - v;
            boffS[2 * t] = excl;
            boffS[2 * t + 1] = excl + h0;
        }
        __syncthreads();
        for (int b = t; b < PBUK; b += 256) {
            gboff[cb * PBUK + b] = boffS[b];
            ghist[cb * PBUK + b] = hist[b];
        }
        __syncthreads();
        for (int b = t; b < PBUK; b += 256) hist[b] = 0;
        __syncthreads();
        // pass 2: scatter from the LDS pack (short dep chain, ILP-8)
        for (int i0 = t; i0 < n; i0 += 2048) {
            u32 wv[8];
            #pragma unroll
            for (int j = 0; j < 8; ++j) {
                int i = i0 + j * 256;
                wv[j] = (i < n) ? epk[i] : 0xFFFFFFFFu;
            }
            #pragma unroll
            for (int j = 0; j < 8; ++j) {
                u32 w = wv[j];
                u32 bk = w >> 23;
                if (bk < PBUK) {
                    int p = atomicAdd(&hist[bk], 1);
                    bedges[base + boffS[bk] + p] = w & 0x7FFFFFu;
                }
            }
        }
    } else {
        // ---- embed tile ----
        u16* acts0 = (u16*)smem;                 // h1 hi  [64][72]
        u16* acts1 = (u16*)smem + 64 * 72;       // h1 lo
        const int l = t & 63;
        const int lr = l & 15, lg = l >> 4;
        const int rowb = (t >> 6) * 16;
        const int nb = (blockIdx.x - SBLK) * 64;
        int nodeA = nb + rowb + lr;
        if (nodeA >= NN) nodeA = NN - 1;         // clamped loads; stores guarded
        const float* xp = x + (size_t)nodeA * DD + lg * 8;

        // ---- stage 1: h1 = relu(x @ w1 + b1), K=128 ----
        f32x4 acc[4];
        #pragma unroll
        for (int tt = 0; tt < 4; ++tt) {
            float b = b1[tt * 16 + lr];
            acc[tt] = (f32x4){b, b, b, b};
        }
        #pragma unroll
        for (int kc = 0; kc < 4; ++kc) {
            float4 v0 = *(const float4*)(xp + kc * 32);
            float4 v1 = *(const float4*)(xp + kc * 32 + 4);
            float vv[8] = {v0.x, v0.y, v0.z, v0.w, v1.x, v1.y, v1.z, v1.w};
            bf16x8 xh, xl;
            #pragma unroll
            for (int j = 0; j < 8; ++j) {
                u16 hi = (u16)f2bf(vv[j]);
                xh[j] = (short)hi;
                xl[j] = (short)(u16)f2bf(vv[j] - bf2f(hi));
            }
            #pragma unroll
            for (int tt = 0; tt < 4; ++tt) {
                const u16* ph = wtb + WT_E1 + (tt * 16 + lr) * 128 + kc * 32 + lg * 8;
                const u16* pl = wtb + WT_E1L + (tt * 16 + lr) * 128 + kc * 32 + lg * 8;
                bf16x8 wh = *(const bf16x8*)ph;
                bf16x8 wl = *(const bf16x8*)pl;
                acc[tt] = __builtin_amdgcn_mfma_f32_16x16x32_bf16(xh, wh, acc[tt], 0, 0, 0);
                acc[tt] = __builtin_amdgcn_mfma_f32_16x16x32_bf16(xl, wh, acc[tt], 0, 0, 0);
                acc[tt] = __builtin_amdgcn_mfma_f32_16x16x32_bf16(xh, wl, acc[tt], 0, 0, 0);
            }
        }
        #pragma unroll
        for (int tt = 0; tt < 4; ++tt)
            #pragma unroll
            for (int r = 0; r < 4; ++r) {
                float v = fmaxf(acc[tt][r], 0.0f);
                u16 hi = (u16)f2bf(v);
                u16 lo = (u16)f2bf(v - bf2f(hi));
                acts0[(rowb + lg * 4 + r) * 72 + tt * 16 + lr] = hi;
                acts1[(rowb + lg * 4 + r) * 72 + tt * 16 + lr] = lo;
            }
        __syncthreads();

        // ---- stage 2: h = h1 @ w2 + b2 (no relu) ----
        bf16x8 c0h = *(const bf16x8*)&acts0[(rowb + lr) * 72 + lg * 8];
        bf16x8 c1h = *(const bf16x8*)&acts0[(rowb + lr) * 72 + 32 + lg * 8];
        bf16x8 c0l = *(const bf16x8*)&acts1[(rowb + lr) * 72 + lg * 8];
        bf16x8 c1l = *(const bf16x8*)&acts1[(rowb + lr) * 72 + 32 + lg * 8];
        f32x4 acc2[4];
        #pragma unroll
        for (int tt = 0; tt < 4; ++tt) {
            float b = b2[tt * 16 + lr];
            acc2[tt] = (f32x4){b, b, b, b};
        }
        #pragma unroll
        for (int tt = 0; tt < 4; ++tt) {
            const u16* ph = wtb + WT_E2 + (tt * 16 + lr) * 64 + lg * 8;
            const u16* pl = wtb + WT_E2L + (tt * 16 + lr) * 64 + lg * 8;
            bf16x8 wh0 = *(const bf16x8*)ph;
            bf16x8 wh1 = *(const bf16x8*)(ph + 32);
            bf16x8 wl0 = *(const bf16x8*)pl;
            bf16x8 wl1 = *(const bf16x8*)(pl + 32);
            acc2[tt] = __builtin_amdgcn_mfma_f32_16x16x32_bf16(c0h, wh0, acc2[tt], 0, 0, 0);
            acc2[tt] = __builtin_amdgcn_mfma_f32_16x16x32_bf16(c1h, wh1, acc2[tt], 0, 0, 0);
            acc2[tt] = __builtin_amdgcn_mfma_f32_16x16x32_bf16(c0l, wh0, acc2[tt], 0, 0, 0);
            acc2[tt] = __builtin_amdgcn_mfma_f32_16x16x32_bf16(c1l, wh1, acc2[tt], 0, 0, 0);
            acc2[tt] = __builtin_amdgcn_mfma_f32_16x16x32_bf16(c0h, wl0, acc2[tt], 0, 0, 0);
            acc2[tt] = __builtin_amdgcn_mfma_f32_16x16x32_bf16(c1h, wl1, acc2[tt], 0, 0, 0);
        }
        #pragma unroll
        for (int tt = 0; tt < 4; ++tt)
            #pragma unroll
            for (int r = 0; r < 4; ++r) {
                int node = nb + rowb + lg * 4 + r;
                if (node < NN)
                    hb[(size_t)node * HH + tt * 16 + lr] = (u16)f2bf(acc2[tt][r]);
            }
    }
}

// ---------------- adjacency build: hoisted descriptors, 4x16-lane segments ----------------

__global__ __launch_bounds__(256) void k_adj(const u32* __restrict__ bedges,
                                             const int* __restrict__ gboff,
                                             const int* __restrict__ ghist,
                                             u16* __restrict__ slots,
                                             int* __restrict__ deg,
                                             float* __restrict__ pooled,
                                             u16* __restrict__ hb,
                                             int* __restrict__ ctr) {
    __shared__ u16 ls[128 * MAXDEG];   // 20 KB
    __shared__ int lc[128];
    const int b = blockIdx.x, t = threadIdx.x;
    const int lane = t & 63, wid = t >> 6;
    if (b < (NG * HH) / 256) pooled[b * 256 + t] = 0.0f;
    if (b == 0) {
        if (t < 32) ((u32*)hb)[NN * (HH / 2) + t] = 0;   // phantom zero row
        else if (t == 32) *ctr = 0;                      // cls last-block counter
    }
    if (t < 128) lc[t] = 0;
    {   // sentinel fill: unused slots point at the phantom zero row
        const u32 sent = ((u32)NN << 16) | (u32)NN;
        u32* lsu = (u32*)ls;
        for (int i = t; i < 128 * MAXDEG / 2; i += 256) lsu[i] = sent;
    }
    // descriptor hoist: lane l holds desc for sb = wid*64 + l (one load each)
    const int sbl = wid * 64 + lane;                     // SBLK == 256 == 4*64
    const int offv = gboff[sbl * PBUK + b];
    const int cntv = ghist[sbl * PBUK + b];
    __syncthreads();
    const int q = lane >> 4, sl = lane & 15;             // 4 segments x 16 lanes
    for (int it = 0; it < 16; ++it) {
        const int idx = it * 4 + q;                      // sb within wave's 64
        const int off = __shfl(offv, idx);
        const int cnt = __shfl(cntv, idx);
        const int gbase = (wid * 64 + idx) * CHUNK + off;
        for (int i = sl; i < cnt; i += 16) {
            u32 p = bedges[gbase + i];
            int o = (int)(p & 127u);
            int src = (int)(p >> 7);
            int pos = atomicAdd(&lc[o], 1);
            if (pos < MAXDEG) ls[o * MAXDEG + pos] = (u16)src;
        }
    }
    __syncthreads();
    u32* gs = (u32*)(slots + (size_t)b * 128 * MAXDEG);
    const u32* lsu = (const u32*)ls;
    for (int i = t; i < 128 * MAXDEG / 2; i += 256) gs[i] = lsu[i];
    if (t < 128) deg[b * 128 + t] = lc[t];
}

// ---------------- Mean aggregation: 2 nodes/wave, 16 u32 gathers in flight ----------------

__global__ __launch_bounds__(256) void k_agg(
    const u16* __restrict__ hb, const int* __restrict__ deg,
    const u16* __restrict__ slots, u16* __restrict__ aggb) {
    const int wid = threadIdx.x >> 6, lane = threadIdx.x & 63;
    const int half = lane >> 5, fl = lane & 31;        // feature-pair index
    const int n0 = blockIdx.x * 8 + wid * 2;
    if (n0 >= NN) return;
    const int n = n0 + half;
    const bool valid = n < NN;
    const int d = valid ? deg[n] : 0;
    const int m = min(d, MAXDEG);
    const int mp = (m + 15) & ~15;                      // sentinel-padded, <= 80
    const u32* row = (const u32*)(slots + (size_t)n * MAXDEG);
    float s0 = 0.0f, s1 = 0.0f;
    for (int e = 0; e < mp; e += 16) {
        const u32* rp = row + (e >> 1);
        uint4 i0 = *(const uint4*)rp;
        uint4 i1 = *(const uint4*)(rp + 4);
        u32 v0 = *(const u32*)(hb + (size_t)(i0.x & 0xffffu) * HH + 2 * fl);
        u32 v1 = *(const u32*)(hb + (size_t)(i0.x >> 16)    * HH + 2 * fl);
        u32 v2 = *(const u32*)(hb + (size_t)(i0.y & 0xffffu) * HH + 2 * fl);
        u32 v3 = *(const u32*)(hb + (size_t)(i0.y >> 16)    * HH + 2 * fl);
        u32 v4 = *(const u32*)(hb + (size_t)(i0.z & 0xffffu) * HH + 2 * fl);
        u32 v5 = *(const u32*)(hb + (size_t)(i0.z >> 16)    * HH + 2 * fl);
        u32 v6 = *(const u32*)(hb + (size_t)(i0.w & 0xffffu) * HH + 2 * fl);
        u32 v7 = *(const u32*)(hb + (size_t)(i0.w >> 16)    * HH + 2 * fl);
        u32 v8 = *(const u32*)(hb + (size_t)(i1.x & 0xffffu) * HH + 2 * fl);
        u32 v9 = *(const u32*)(hb + (size_t)(i1.x >> 16)    * HH + 2 * fl);
        u32 va = *(const u32*)(hb + (size_t)(i1.y & 0xffffu) * HH + 2 * fl);
        u32 vb = *(const u32*)(hb + (size_t)(i1.y >> 16)    * HH + 2 * fl);
        u32 vc = *(const u32*)(hb + (size_t)(i1.z & 0xffffu) * HH + 2 * fl);
        u32 vd = *(const u32*)(hb + (size_t)(i1.z >> 16)    * HH + 2 * fl);
        u32 ve = *(const u32*)(hb + (size_t)(i1.w & 0xffffu) * HH + 2 * fl);
        u32 vf = *(const u32*)(hb + (size_t)(i1.w >> 16)    * HH + 2 * fl);
        s0 += ((bf2f((u16)(v0 & 0xffffu)) + bf2f((u16)(v1 & 0xffffu)))
             + (bf2f((u16)(v2 & 0xffffu)) + bf2f((u16)(v3 & 0xffffu))))
            + ((bf2f((u16)(v4 & 0xffffu)) + bf2f((u16)(v5 & 0xffffu)))
             + (bf2f((u16)(v6 & 0xffffu)) + bf2f((u16)(v7 & 0xffffu))));
        s0 += ((bf2f((u16)(v8 & 0xffffu)) + bf2f((u16)(v9 & 0xffffu)))
             + (bf2f((u16)(va & 0xffffu)) + bf2f((u16)(vb & 0xffffu))))
            + ((bf2f((u16)(vc & 0xffffu)) + bf2f((u16)(vd & 0xffffu)))
             + (bf2f((u16)(ve & 0xffffu)) + bf2f((u16)(vf & 0xffffu))));
        s1 += ((bf2f((u16)(v0 >> 16)) + bf2f((u16)(v1 >> 16)))
             + (bf2f((u16)(v2 >> 16)) + bf2f((u16)(v3 >> 16))))
            + ((bf2f((u16)(v4 >> 16)) + bf2f((u16)(v5 >> 16)))
             + (bf2f((u16)(v6 >> 16)) + bf2f((u16)(v7 >> 16))));
        s1 += ((bf2f((u16)(v8 >> 16)) + bf2f((u16)(v9 >> 16)))
             + (bf2f((u16)(va >> 16)) + bf2f((u16)(vb >> 16))))
            + ((bf2f((u16)(vc >> 16)) + bf2f((u16)(vd >> 16)))
             + (bf2f((u16)(ve >> 16)) + bf2f((u16)(vf >> 16))));
    }
    if (valid) {
        float inv = 1.0f / (float)max(d, 1);
        u32 p = f2bf(s0 * inv) | (f2bf(s1 * inv) << 16);
        ((u32*)aggb)[(size_t)n * (HH / 2) + fl] = p;
    }
}

// ---------------- Dense per-layer on MFMA; L1 fuses pool + last-block classifier ----------------

__global__ __launch_bounds__(256) void k_dense(
    u16* __restrict__ hb, const u16* __restrict__ aggb,
    const u16* __restrict__ wt,          // layer base in hi plane; lo at +WT_LO
    const float* __restrict__ relb,
    const float* __restrict__ pb1, const float* __restrict__ pb2,
    const int* __restrict__ batch, float* __restrict__ pooled,
    int* __restrict__ ctr,
    const float* __restrict__ clsw, const float* __restrict__ clsb,
    float* __restrict__ outp, int do_pool) {
    __shared__ __align__(16) char smemd[NG * HH * 4];   // 32 KB: acts[2][64][72] | cls plbuf
    u16 (*acts)[64][72] = (u16 (*)[64][72])smemd;
    const int t = threadIdx.x;
    const int w = t >> 6;
    const int l = t & 63;
    const int lr = l & 15, lg = l >> 4;
    const int rowb = w * 16;
    const int nb = blockIdx.x * 64;
    int nodeA = nb + rowb + lr;
    if (nodeA >= NN) nodeA = NN - 1;          // clamped loads; stores guarded

    const u16* w_rel = wt;
    const u16* w_root = wt + 4096;
    const u16* w_p1  = wt + 2 * 4096;
    const u16* w_p2  = wt + 3 * 4096;

    // ---- stage 1: conv = aggb @ rel + relb + hb @ root (no relu) ----
    const u16* agp = aggb + (size_t)nodeA * HH + lg * 8;
    const u16* hbp = hb   + (size_t)nodeA * HH + lg * 8;
    bf16x8 a0 = *(const bf16x8*)agp;
    bf16x8 a1 = *(const bf16x8*)(agp + 32);
    bf16x8 h0 = *(const bf16x8*)hbp;
    bf16x8 h1 = *(const bf16x8*)(hbp + 32);

    f32x4 acc[4];
    #pragma unroll
    for (int tt = 0; tt < 4; ++tt) {
        float b = relb[tt * 16 + lr];
        acc[tt] = (f32x4){b, b, b, b};
    }
    #pragma unroll
    for (int tt = 0; tt < 4; ++tt) {
        const u16* pr = w_rel  + (tt * 16 + lr) * 64 + lg * 8;
        const u16* po = w_root + (tt * 16 + lr) * 64 + lg * 8;
        acc[tt] = __builtin_amdgcn_mfma_f32_16x16x32_bf16(a0, *(const bf16x8*)pr,                acc[tt], 0, 0, 0);
        acc[tt] = __builtin_amdgcn_mfma_f32_16x16x32_bf16(a1, *(const bf16x8*)(pr + 32),         acc[tt], 0, 0, 0);
        acc[tt] = __builtin_amdgcn_mfma_f32_16x16x32_bf16(a0, *(const bf16x8*)(pr + WT_LO),      acc[tt], 0, 0, 0);
        acc[tt] = __builtin_amdgcn_mfma_f32_16x16x32_bf16(a1, *(const bf16x8*)(pr + WT_LO + 32), acc[tt], 0, 0, 0);
        acc[tt] = __builtin_amdgcn_mfma_f32_16x16x32_bf16(h0, *(const bf16x8*)po,                acc[tt], 0, 0, 0);
        acc[tt] = __builtin_amdgcn_mfma_f32_16x16x32_bf16(h1, *(const bf16x8*)(po + 32),         acc[tt], 0, 0, 0);
        acc[tt] = __builtin_amdgcn_mfma_f32_16x16x32_bf16(h0, *(const bf16x8*)(po + WT_LO),      acc[tt], 0, 0, 0);
        acc[tt] = __builtin_amdgcn_mfma_f32_16x16x32_bf16(h1, *(const bf16x8*)(po + WT_LO + 32), acc[tt], 0, 0, 0);
    }
    #pragma unroll
    for (int tt = 0; tt < 4; ++tt)
        #pragma unroll
        for (int r = 0; r < 4; ++r)
            acts[0][rowb + lg * 4 + r][tt * 16 + lr] = (u16)f2bf(acc[tt][r]);
    __syncthreads();

    // ---- stage 2: hidden = relu(conv @ pw1 + pb1) ----
    bf16x8 c0 = *(const bf16x8*)&acts[0][rowb + lr][lg * 8];
    bf16x8 c1 = *(const bf16x8*)&acts[0][rowb + lr][32 + lg * 8];
    f32x4 acc2[4];
    #pragma unroll
    for (int tt = 0; tt < 4; ++tt) {
        float b = pb1[tt * 16 + lr];
        acc2[tt] = (f32x4){b, b, b, b};
    }
    #pragma unroll
    for (int tt = 0; tt < 4; ++tt) {
        const u16* pr = w_p1 + (tt * 16 + lr) * 64 + lg * 8;
        acc2[tt] = __builtin_amdgcn_mfma_f32_16x16x32_bf16(c0, *(const bf16x8*)pr,                acc2[tt], 0, 0, 0);
        acc2[tt] = __builtin_amdgcn_mfma_f32_16x16x32_bf16(c1, *(const bf16x8*)(pr + 32),         acc2[tt], 0, 0, 0);
        acc2[tt] = __builtin_amdgcn_mfma_f32_16x16x32_bf16(c0, *(const bf16x8*)(pr + WT_LO),      acc2[tt], 0, 0, 0);
        acc2[tt] = __builtin_amdgcn_mfma_f32_16x16x32_bf16(c1, *(const bf16x8*)(pr + WT_LO + 32), acc2[tt], 0, 0, 0);
    }
    #pragma unroll
    for (int tt = 0; tt < 4; ++tt)
        #pragma unroll
        for (int r = 0; r < 4; ++r)
            acts[1][rowb + lg * 4 + r][tt * 16 + lr] = (u16)f2bf(fmaxf(acc2[tt][r], 0.0f));
    __syncthreads();

    // ---- stage 3: h = relu(hidden @ pw2 + pb2) ----
    bf16x8 d0 = *(const bf16x8*)&acts[1][rowb + lr][lg * 8];
    bf16x8 d1 = *(const bf16x8*)&acts[1][rowb + lr][32 + lg * 8];
    f32x4 acc3[4];
    #pragma unroll
    for (int tt = 0; tt < 4; ++tt) {
        float b = pb2[tt * 16 + lr];
        acc3[tt] = (f32x4){b, b, b, b};
    }
    #pragma unroll
    for (int tt = 0; tt < 4; ++tt) {
        const u16* pr = w_p2 + (tt * 16 + lr) * 64 + lg * 8;
        acc3[tt] = __builtin_amdgcn_mfma_f32_16x16x32_bf16(d0, *(const bf16x8*)pr,                acc3[tt], 0, 0, 0);
        acc3[tt] = __builtin_amdgcn_mfma_f32_16x16x32_bf16(d1, *(const bf16x8*)(pr + 32),         acc3[tt], 0, 0, 0);
        acc3[tt] = __builtin_amdgcn_mfma_f32_16x16x32_bf16(d0, *(const bf16x8*)(pr + WT_LO),      acc3[tt], 0, 0, 0);
        acc3[tt] = __builtin_amdgcn_mfma_f32_16x16x32_bf16(d1, *(const bf16x8*)(pr + WT_LO + 32), acc3[tt], 0, 0, 0);
    }

    if (!do_pool) {
        #pragma unroll
        for (int tt = 0; tt < 4; ++tt)
            #pragma unroll
            for (int r = 0; r < 4; ++r) {
                int node = nb + rowb + lg * 4 + r;
                if (node < NN)
                    hb[(size_t)node * HH + tt * 16 + lr] = (u16)f2bf(fmaxf(acc3[tt][r], 0.0f));
            }
        return;
    }

    // ---- fused mean-pool numerator: pre-reduce 64 nodes in LDS ----
    #pragma unroll
    for (int tt = 0; tt < 4; ++tt)
        #pragma unroll
        for (int r = 0; r < 4; ++r)
            acts[0][rowb + lg * 4 + r][tt * 16 + lr] = (u16)f2bf(fmaxf(acc3[tt][r], 0.0f));
    __syncthreads();
    if (t < HH) {
        const int f = t;
        const int n1 = min(64, NN - nb);
        int cur = batch[nb];
        float s = 0.0f;
        for (int i = 0; i < n1; ++i) {
            int g = batch[nb + i];   // sorted; broadcast read
            if (g != cur) {
                if ((unsigned)cur < NG) atomicAdd(&pooled[cur * HH + f], s);
                s = 0.0f; cur = g;
            }
            s += bf2f(acts[0][i][f]);
        }
        if ((unsigned)cur < NG) atomicAdd(&pooled[cur * HH + f], s);
    }

    // ---- last-block classifier (validated pattern from R26 kernel) ----
    __threadfence();
    __shared__ int lastF;
    if (t == 0) lastF = (atomicAdd(ctr, 1) == NTILES - 1);
    __syncthreads();
    if (!lastF) return;

    __shared__ float ginv[NG];
    if (t < NG) {
        int g = t;
        int lo = 0, hi = NN;
        while (lo < hi) { int mid = (lo + hi) >> 1; if (batch[mid] < g) lo = mid + 1; else hi = mid; }
        int beg = lo; lo = 0; hi = NN;
        while (lo < hi) { int mid = (lo + hi) >> 1; if (batch[mid] < g + 1) lo = mid + 1; else hi = mid; }
        ginv[g] = 1.0f / (float)max(lo - beg, 1);
    }
    float* plbuf = (float*)smemd;            // [HH][NG] transposed, 32 KB
    #pragma unroll
    for (int j = 0; j < (NG * HH) / 256; ++j) {
        int idx = t * 32 + j;
        int g = idx >> 6, k = idx & 63;
        float v = atomicAdd(&pooled[idx], 0.0f);   // coherent read (device scope)
        plbuf[k * NG + g] = v;
    }
    __syncthreads();
    for (int o = t; o < NG * NCLS; o += 256) {
        int g = o / NCLS, c = o - g * NCLS;
        float s = 0.0f;
        #pragma unroll 8
        for (int k = 0; k < HH; ++k)
            s += plbuf[k * NG + g] * clsw[k * NCLS + c];
        outp[o] = clsb[c] + s * ginv[g];
    }
}

// ---------------- Launch ----------------

extern "C" void kernel_launch(void* const* d_in, const int* in_sizes, int n_in,
                              void* d_out, int out_size, void* d_ws, size_t ws_size,
                              hipStream_t stream) {
    const float* x      = (const float*)d_in[0];
    const int*   ei     = (const int*)d_in[1];    // int32 [2,E]
    const int*   batch  = (const int*)d_in[2];    // int32 [N], sorted
    const float* emb_w1 = (const float*)d_in[3];
    const float* emb_b1 = (const float*)d_in[4];
    const float* emb_w2 = (const float*)d_in[5];
    const float* emb_b2 = (const float*)d_in[6];
    const float* rel_w  = (const float*)d_in[7];
    const float* rel_b  = (const float*)d_in[8];
    const float* root_w = (const float*)d_in[9];
    const float* pw1    = (const float*)d_in[10];
    const float* pb1    = (const float*)d_in[11];
    const float* pw2    = (const float*)d_in[12];
    const float* pb2    = (const float*)d_in[13];
    const float* cls_w  = (const float*)d_in[14];
    const float* cls_b  = (const float*)d_in[15];
    float* out = (float*)d_out;

    // Workspace (~23 MB): hb 6.4 | aggb 6.4 (aliases bedges 5) | slots 8 | wtb 0.18 | misc 1
    char* ws = (char*)d_ws;
    size_t off = 0;
    auto alloc = [&](size_t bytes) -> void* {
        off = (off + 255) & ~(size_t)255;
        void* p = ws + off;
        off += bytes;
        return p;
    };
    u16*   hb     = (u16*)alloc((size_t)(NN + 1) * HH * 2);   // +1 phantom zero row
    u16*   aggb   = (u16*)alloc((size_t)NN * HH * 2);         // bf16 agg
    u32*   bedges = (u32*)aggb;                               // alias: bedges dead before aggb write
    u16*   slots  = (u16*)alloc((size_t)NDP * MAXDEG * 2);
    int*   deg    = (int*)alloc((size_t)NDP * 4);
    int*   gboff  = (int*)alloc((size_t)SBLK * PBUK * 4);
    int*   ghist  = (int*)alloc((size_t)SBLK * PBUK * 4);
    float* pooled = (float*)alloc((size_t)NG * HH * 4);
    int*   ctr    = (int*)alloc(256);
    u16*   wtb    = (u16*)alloc((size_t)WT_TOT * 2);

    // launch 0: weight transpose + hi/lo split (all 10 matrices)
    k_wprep<<<10, 256, 0, stream>>>(rel_w, root_w, pw1, pw2, emb_w1, emb_w2, wtb);
    // launch 1: psort chunks (first) + embed tiles (MFMA), block-partitioned
    k_embed_psort<<<SBLK + NTILES, 256, 0, stream>>>(
        x, emb_b1, emb_b2, wtb, hb, ei, bedges, gboff, ghist);
    // launch 2: adjacency (+ zero pooled, phantom row, cls counter)
    k_adj<<<PBUK, 256, 0, stream>>>(bedges, gboff, ghist, slots, deg, pooled, hb, ctr);
    // layer 0 (dense in-place on hb)
    k_agg<<<(NN + 7) / 8, 256, 0, stream>>>(hb, deg, slots, aggb);
    k_dense<<<NTILES, 256, 0, stream>>>(hb, aggb, wtb, rel_b, pb1, pb2, batch, pooled,
                                        ctr, cls_w, cls_b, out, 0);
    // layer 1 (fused pool + last-block classifier)
    k_agg<<<(NN + 7) / 8, 256, 0, stream>>>(hb, deg, slots, aggb);
    k_dense<<<NTILES, 256, 0, stream>>>(hb, aggb, wtb + 4 * 4096,
                                        rel_b + HH, pb1 + HH, pb2 + HH, batch, pooled,
                                        ctr, cls_w, cls_b, out, 1);
}

// Round 11
// 261.625 us; speedup vs baseline: 1.2341x; 1.2341x over previous
//
#include <hip/hip_runtime.h>

typedef unsigned int u32;
typedef unsigned short u16;

#define NN 50000
#define EE 1250000
#define DD 128
#define HH 64
#define NCLS 10
#define NG 128
#define MAXDEG 80                    // Poisson(25): P(deg>=80) ~ 0

#define NTILES ((NN + 63) / 64)     // 782

#define PBUK 392                     // buckets = dst>>7
#define SBLK 256                     // sort chunks
#define CHUNK ((EE + SBLK - 1) / SBLK)  // 4883
#define NDP  (PBUK * 128)            // 50176
#define EPKB ((CHUNK * 4 + 15) & ~15)   // 19536 B LDS edge cache per psort chunk

// wtb layout (u16 units): layer hi [8][4096] | layer lo [8][4096] | e1 hi [64][128]
//                         | e1 lo | e2 hi [64][64] | e2 lo
#define WT_LO  (8 * 4096)            // 32768
#define WT_E1  (16 * 4096)           // 65536
#define WT_E1L (WT_E1 + 8192)        // 73728
#define WT_E2  (WT_E1 + 16384)       // 81920
#define WT_E2L (WT_E2 + 4096)        // 86016
#define WT_TOT (WT_E2 + 8192)        // 90112 u16 = 176 KB

// Round-2: int inputs are int32. ei int32 [2,E]: src=ei[e], dst=ei[EE+e].
// Round-3: no ReLU between GraphConv out and post-MLP.
// Round-7..10: adjacency via per-block counting sort (full-line writes only).
// Round-16: no coop grid.sync() on 8 non-coherent XCDs.
// Round-19: fp32 h dropped (bf16 shadow).
// Round-20: k_dense on MFMA bf16 16x16x32; weights hi/lo split.
// Round-21: embed GEMM on MFMA; k_wprep hoisted; sentinel-padded slots.
// Round-22: ILP lesson -- latency-bound gathers need max outstanding loads/wave.
// Round-24: psort-first + SBLK 256 (LDS 22.2KB).
// Round-25: k_adj hoisted descriptors + 4x16-lane segments (59.5 -> ~20us).
//   ==> THIS configuration measured 262.4us (best).
// Round-26: agg fused into dense REGRESSED (130us). REVERTED.
// Round-27..28: h plane-split + 2-pass gather REGRESSED (+18us). REVERTED.
// Round-29: k_cls fused via last-block __threadfence() REGRESSED (+60us):
//   782 device-scope fences = per-block L2 writeback/invalidate on 8
//   non-coherent XCDs -> dense-L1 ran 112us with ALL pipes <2% (latency-
//   poisoned). Lesson: per-block device-scope fences cost ~100us here;
//   the CUDA "last-block" idiom does not transfer. REVERTED.
// Round-30 (this): exact revert to the Round-25/round-6 winner (262.4us).

__device__ __forceinline__ u32 f2bf(float f) {           // RNE fp32->bf16
    u32 u = __float_as_uint(f);
    return (u + 0x7FFFu + ((u >> 16) & 1u)) >> 16;
}
__device__ __forceinline__ float bf2f(u16 v) {
    return __uint_as_float(((u32)v) << 16);
}

typedef __attribute__((ext_vector_type(8))) short bf16x8;   // 8 bf16 = 4 VGPR
typedef __attribute__((ext_vector_type(4))) float f32x4;

// ---------------- weight prep: transpose [k][n] -> [n][k], split bf16 hi/lo ----------------

__global__ __launch_bounds__(256) void k_wprep(
    const float* __restrict__ rel_w, const float* __restrict__ root_w,
    const float* __restrict__ pw1, const float* __restrict__ pw2,
    const float* __restrict__ ew1, const float* __restrict__ ew2,
    u16* __restrict__ wtb) {
    __shared__ float ldsf[128 * 65];                     // 33280 B (e1 worst case)
    const int t = threadIdx.x;
    const int m = blockIdx.x;                            // 0..7 layer mats, 8=e1, 9=e2
    if (m < 8) {
        const int layer = m >> 2, which = m & 3;
        const float* srcw =
            (which == 0 ? rel_w : which == 1 ? root_w : which == 2 ? pw1 : pw2)
            + (size_t)layer * HH * HH;
        #pragma unroll
        for (int r = 0; r < 16; ++r) {
            int idx = r * 256 + t;
            int k = idx >> 6, n = idx & 63;
            ldsf[k * 65 + n] = srcw[idx];                // coalesced read
        }
        __syncthreads();
        #pragma unroll
        for (int r = 0; r < 16; ++r) {
            int idx = r * 256 + t;
            int n = idx >> 6, k = idx & 63;
            float v = ldsf[k * 65 + n];                  // stride 65 -> conflict-free
            u16 hi = (u16)f2bf(v);
            u16 lo = (u16)f2bf(v - bf2f(hi));
            wtb[m * 4096 + idx] = hi;
            wtb[WT_LO + m * 4096 + idx] = lo;
        }
    } else if (m == 8) {                                 // emb_w1: [128][64] -> [64][128]
        #pragma unroll
        for (int r = 0; r < 32; ++r) {
            int idx = r * 256 + t;
            int k = idx >> 6, n = idx & 63;
            ldsf[k * 65 + n] = ew1[idx];
        }
        __syncthreads();
        #pragma unroll
        for (int r = 0; r < 32; ++r) {
            int idx = r * 256 + t;
            int n = idx >> 7, k = idx & 127;
            float v = ldsf[k * 65 + n];
            u16 hi = (u16)f2bf(v);
            u16 lo = (u16)f2bf(v - bf2f(hi));
            wtb[WT_E1 + idx] = hi;
            wtb[WT_E1L + idx] = lo;
        }
    } else {                                             // emb_w2: 64x64
        #pragma unroll
        for (int r = 0; r < 16; ++r) {
            int idx = r * 256 + t;
            int k = idx >> 6, n = idx & 63;
            ldsf[k * 65 + n] = ew2[idx];
        }
        __syncthreads();
        #pragma unroll
        for (int r = 0; r < 16; ++r) {
            int idx = r * 256 + t;
            int n = idx >> 6, k = idx & 63;
            float v = ldsf[k * 65 + n];
            u16 hi = (u16)f2bf(v);
            u16 lo = (u16)f2bf(v - bf2f(hi));
            wtb[WT_E2 + idx] = hi;
            wtb[WT_E2L + idx] = lo;
        }
    }
}

// ---------------- merged launch 1: psort chunks FIRST, then embed tiles (MFMA) ----------------
// Frag layouts (mfma_f32_16x16x32_bf16, verified):
//   A: lane l -> row l&15,  k = 8*(l>>4)+j (16B contiguous)
//   B: lane l -> col l&15,  k = 8*(l>>4)+j   (weights pre-transposed [n][k])
//   C: lane l -> col l&15,  row = 4*(l>>4)+r
// x and h1 split hi/lo bf16 -> embed is exact to ~2^-17.

__global__ __launch_bounds__(256) void k_embed_psort(
    const float* __restrict__ x,
    const float* __restrict__ b1, const float* __restrict__ b2,
    const u16* __restrict__ wtb,
    u16* __restrict__ hb,
    const int* __restrict__ ei, u32* __restrict__ bedges,
    int* __restrict__ gboff, int* __restrict__ ghist) {
    __shared__ __align__(16) char smem[EPKB + PBUK * 8 + 32];   // 22.2 KB
    const int t = threadIdx.x;

    if (blockIdx.x < SBLK) {
        // ---- psort chunk (long pole: starts at t=0 on every CU) ----
        u32* epk   = (u32*)smem;                 // packed edge cache [CHUNK]
        int* hist  = (int*)(smem + EPKB);
        int* boffS = hist + PBUK;
        int* wsum  = boffS + PBUK;
        const int cb = blockIdx.x;
        const int base = cb * CHUNK;
        const int n = min(CHUNK, EE - base);

        for (int b = t; b < PBUK; b += 256) hist[b] = 0;
        __syncthreads();
        // pass 1: pack edges into LDS + histogram (ILP-8 strided loads)
        for (int i0 = t; i0 < n; i0 += 2048) {
            int sV[8], dV[8];
            #pragma unroll
            for (int j = 0; j < 8; ++j) {
                int i = i0 + j * 256;
                sV[j] = -1; dV[j] = -1;
                if (i < n) { sV[j] = ei[base + i]; dV[j] = ei[EE + base + i]; }
            }
            #pragma unroll
            for (int j = 0; j < 8; ++j) {
                int i = i0 + j * 256;
                if (i < n) {
                    bool ok = (unsigned)sV[j] < NN && (unsigned)dV[j] < NN;
                    u32 w = ok ? (((u32)(dV[j] >> 7) << 23) | ((u32)sV[j] << 7) | (u32)(dV[j] & 127))
                               : 0xFFFFFFFFu;
                    epk[i] = w;
                    if (ok) atomicAdd(&hist[dV[j] >> 7], 1);
                }
            }
        }
        __syncthreads();
        int v = 0, h0 = 0;
        if (t < PBUK / 2) { h0 = hist[2 * t]; v = h0 + hist[2 * t + 1]; }
        int lane = t & 63, wd = t >> 6;
        int incl = v;
        #pragma unroll
        for (int d = 1; d < 64; d <<= 1) {
            int tt = __shfl_up(incl, d);
            if (lane >= d) incl += tt;
        }
        if (lane == 63) wsum[wd] = incl;
        __syncthreads();
        int woff = 0;
        for (int w = 0; w < wd; ++w) woff += wsum[w];
        if (t < PBUK / 2) {
            int excl = woff + incl - v;
            boffS[2 * t] = excl;
            boffS[2 * t + 1] = excl + h0;
        }
        __syncthreads();
        for (int b = t; b < PBUK; b += 256) {
            gboff[cb * PBUK + b] = boffS[b];
            ghist[cb * PBUK + b] = hist[b];
        }
        __syncthreads();
        for (int b = t; b < PBUK; b += 256) hist[b] = 0;
        __syncthreads();
        // pass 2: scatter from the LDS pack (short dep chain, ILP-8)
        for (int i0 = t; i0 < n; i0 += 2048) {
            u32 wv[8];
            #pragma unroll
            for (int j = 0; j < 8; ++j) {
                int i = i0 + j * 256;
                wv[j] = (i < n) ? epk[i] : 0xFFFFFFFFu;
            }
            #pragma unroll
            for (int j = 0; j < 8; ++j) {
                u32 w = wv[j];
                u32 bk = w >> 23;
                if (bk < PBUK) {
                    int p = atomicAdd(&hist[bk], 1);
                    bedges[base + boffS[bk] + p] = w & 0x7FFFFFu;
                }
            }
        }
    } else {
        // ---- embed tile ----
        u16* acts0 = (u16*)smem;                 // h1 hi  [64][72]
        u16* acts1 = (u16*)smem + 64 * 72;       // h1 lo
        const int l = t & 63;
        const int lr = l & 15, lg = l >> 4;
        const int rowb = (t >> 6) * 16;
        const int nb = (blockIdx.x - SBLK) * 64;
        int nodeA = nb + rowb + lr;
        if (nodeA >= NN) nodeA = NN - 1;         // clamped loads; stores guarded
        const float* xp = x + (size_t)nodeA * DD + lg * 8;

        // ---- stage 1: h1 = relu(x @ w1 + b1), K=128 ----
        f32x4 acc[4];
        #pragma unroll
        for (int tt = 0; tt < 4; ++tt) {
            float b = b1[tt * 16 + lr];
            acc[tt] = (f32x4){b, b, b, b};
        }
        #pragma unroll
        for (int kc = 0; kc < 4; ++kc) {
            float4 v0 = *(const float4*)(xp + kc * 32);
            float4 v1 = *(const float4*)(xp + kc * 32 + 4);
            float vv[8] = {v0.x, v0.y, v0.z, v0.w, v1.x, v1.y, v1.z, v1.w};
            bf16x8 xh, xl;
            #pragma unroll
            for (int j = 0; j < 8; ++j) {
                u16 hi = (u16)f2bf(vv[j]);
                xh[j] = (short)hi;
                xl[j] = (short)(u16)f2bf(vv[j] - bf2f(hi));
            }
            #pragma unroll
            for (int tt = 0; tt < 4; ++tt) {
                const u16* ph = wtb + WT_E1 + (tt * 16 + lr) * 128 + kc * 32 + lg * 8;
                const u16* pl = wtb + WT_E1L + (tt * 16 + lr) * 128 + kc * 32 + lg * 8;
                bf16x8 wh = *(const bf16x8*)ph;
                bf16x8 wl = *(const bf16x8*)pl;
                acc[tt] = __builtin_amdgcn_mfma_f32_16x16x32_bf16(xh, wh, acc[tt], 0, 0, 0);
                acc[tt] = __builtin_amdgcn_mfma_f32_16x16x32_bf16(xl, wh, acc[tt], 0, 0, 0);
                acc[tt] = __builtin_amdgcn_mfma_f32_16x16x32_bf16(xh, wl, acc[tt], 0, 0, 0);
            }
        }
        #pragma unroll
        for (int tt = 0; tt < 4; ++tt)
            #pragma unroll
            for (int r = 0; r < 4; ++r) {
                float v = fmaxf(acc[tt][r], 0.0f);
                u16 hi = (u16)f2bf(v);
                u16 lo = (u16)f2bf(v - bf2f(hi));
                acts0[(rowb + lg * 4 + r) * 72 + tt * 16 + lr] = hi;
                acts1[(rowb + lg * 4 + r) * 72 + tt * 16 + lr] = lo;
            }
        __syncthreads();

        // ---- stage 2: h = h1 @ w2 + b2 (no relu) ----
        bf16x8 c0h = *(const bf16x8*)&acts0[(rowb + lr) * 72 + lg * 8];
        bf16x8 c1h = *(const bf16x8*)&acts0[(rowb + lr) * 72 + 32 + lg * 8];
        bf16x8 c0l = *(const bf16x8*)&acts1[(rowb + lr) * 72 + lg * 8];
        bf16x8 c1l = *(const bf16x8*)&acts1[(rowb + lr) * 72 + 32 + lg * 8];
        f32x4 acc2[4];
        #pragma unroll
        for (int tt = 0; tt < 4; ++tt) {
            float b = b2[tt * 16 + lr];
            acc2[tt] = (f32x4){b, b, b, b};
        }
        #pragma unroll
        for (int tt = 0; tt < 4; ++tt) {
            const u16* ph = wtb + WT_E2 + (tt * 16 + lr) * 64 + lg * 8;
            const u16* pl = wtb + WT_E2L + (tt * 16 + lr) * 64 + lg * 8;
            bf16x8 wh0 = *(const bf16x8*)ph;
            bf16x8 wh1 = *(const bf16x8*)(ph + 32);
            bf16x8 wl0 = *(const bf16x8*)pl;
            bf16x8 wl1 = *(const bf16x8*)(pl + 32);
            acc2[tt] = __builtin_amdgcn_mfma_f32_16x16x32_bf16(c0h, wh0, acc2[tt], 0, 0, 0);
            acc2[tt] = __builtin_amdgcn_mfma_f32_16x16x32_bf16(c1h, wh1, acc2[tt], 0, 0, 0);
            acc2[tt] = __builtin_amdgcn_mfma_f32_16x16x32_bf16(c0l, wh0, acc2[tt], 0, 0, 0);
            acc2[tt] = __builtin_amdgcn_mfma_f32_16x16x32_bf16(c1l, wh1, acc2[tt], 0, 0, 0);
            acc2[tt] = __builtin_amdgcn_mfma_f32_16x16x32_bf16(c0h, wl0, acc2[tt], 0, 0, 0);
            acc2[tt] = __builtin_amdgcn_mfma_f32_16x16x32_bf16(c1h, wl1, acc2[tt], 0, 0, 0);
        }
        #pragma unroll
        for (int tt = 0; tt < 4; ++tt)
            #pragma unroll
            for (int r = 0; r < 4; ++r) {
                int node = nb + rowb + lg * 4 + r;
                if (node < NN)
                    hb[(size_t)node * HH + tt * 16 + lr] = (u16)f2bf(acc2[tt][r]);
            }
    }
}

// ---------------- adjacency build: hoisted descriptors, 4x16-lane segments ----------------

__global__ __launch_bounds__(256) void k_adj(const u32* __restrict__ bedges,
                                             const int* __restrict__ gboff,
                                             const int* __restrict__ ghist,
                                             u16* __restrict__ slots,
                                             int* __restrict__ deg,
                                             float* __restrict__ pooled,
                                             u16* __restrict__ hb) {
    __shared__ u16 ls[128 * MAXDEG];   // 20 KB
    __shared__ int lc[128];
    const int b = blockIdx.x, t = threadIdx.x;
    const int lane = t & 63, wid = t >> 6;
    if (b < (NG * HH) / 256) pooled[b * 256 + t] = 0.0f;
    if (b == 0 && t < 32) ((u32*)hb)[NN * (HH / 2) + t] = 0;   // phantom zero row
    if (t < 128) lc[t] = 0;
    {   // sentinel fill: unused slots point at the phantom zero row
        const u32 sent = ((u32)NN << 16) | (u32)NN;
        u32* lsu = (u32*)ls;
        for (int i = t; i < 128 * MAXDEG / 2; i += 256) lsu[i] = sent;
    }
    // descriptor hoist: lane l holds desc for sb = wid*64 + l (one load each)
    const int sbl = wid * 64 + lane;                     // SBLK == 256 == 4*64
    const int offv = gboff[sbl * PBUK + b];
    const int cntv = ghist[sbl * PBUK + b];
    __syncthreads();
    const int q = lane >> 4, sl = lane & 15;             // 4 segments x 16 lanes
    for (int it = 0; it < 16; ++it) {
        const int idx = it * 4 + q;                      // sb within wave's 64
        const int off = __shfl(offv, idx);
        const int cnt = __shfl(cntv, idx);
        const int gbase = (wid * 64 + idx) * CHUNK + off;
        for (int i = sl; i < cnt; i += 16) {
            u32 p = bedges[gbase + i];
            int o = (int)(p & 127u);
            int src = (int)(p >> 7);
            int pos = atomicAdd(&lc[o], 1);
            if (pos < MAXDEG) ls[o * MAXDEG + pos] = (u16)src;
        }
    }
    __syncthreads();
    u32* gs = (u32*)(slots + (size_t)b * 128 * MAXDEG);
    const u32* lsu = (const u32*)ls;
    for (int i = t; i < 128 * MAXDEG / 2; i += 256) gs[i] = lsu[i];
    if (t < 128) deg[b * 128 + t] = lc[t];
}

// ---------------- Mean aggregation: 2 nodes/wave, 16 u32 gathers in flight ----------------

__global__ __launch_bounds__(256) void k_agg(
    const u16* __restrict__ hb, const int* __restrict__ deg,
    const u16* __restrict__ slots, u16* __restrict__ aggb) {
    const int wid = threadIdx.x >> 6, lane = threadIdx.x & 63;
    const int half = lane >> 5, fl = lane & 31;        // feature-pair index
    const int n0 = blockIdx.x * 8 + wid * 2;
    if (n0 >= NN) return;
    const int n = n0 + half;
    const bool valid = n < NN;
    const int d = valid ? deg[n] : 0;
    const int m = min(d, MAXDEG);
    const int mp = (m + 15) & ~15;                      // sentinel-padded, <= 80
    const u32* row = (const u32*)(slots + (size_t)n * MAXDEG);
    float s0 = 0.0f, s1 = 0.0f;
    for (int e = 0; e < mp; e += 16) {
        const u32* rp = row + (e >> 1);
        uint4 i0 = *(const uint4*)rp;
        uint4 i1 = *(const uint4*)(rp + 4);
        u32 v0 = *(const u32*)(hb + (size_t)(i0.x & 0xffffu) * HH + 2 * fl);
        u32 v1 = *(const u32*)(hb + (size_t)(i0.x >> 16)    * HH + 2 * fl);
        u32 v2 = *(const u32*)(hb + (size_t)(i0.y & 0xffffu) * HH + 2 * fl);
        u32 v3 = *(const u32*)(hb + (size_t)(i0.y >> 16)    * HH + 2 * fl);
        u32 v4 = *(const u32*)(hb + (size_t)(i0.z & 0xffffu) * HH + 2 * fl);
        u32 v5 = *(const u32*)(hb + (size_t)(i0.z >> 16)    * HH + 2 * fl);
        u32 v6 = *(const u32*)(hb + (size_t)(i0.w & 0xffffu) * HH + 2 * fl);
        u32 v7 = *(const u32*)(hb + (size_t)(i0.w >> 16)    * HH + 2 * fl);
        u32 v8 = *(const u32*)(hb + (size_t)(i1.x & 0xffffu) * HH + 2 * fl);
        u32 v9 = *(const u32*)(hb + (size_t)(i1.x >> 16)    * HH + 2 * fl);
        u32 va = *(const u32*)(hb + (size_t)(i1.y & 0xffffu) * HH + 2 * fl);
        u32 vb = *(const u32*)(hb + (size_t)(i1.y >> 16)    * HH + 2 * fl);
        u32 vc = *(const u32*)(hb + (size_t)(i1.z & 0xffffu) * HH + 2 * fl);
        u32 vd = *(const u32*)(hb + (size_t)(i1.z >> 16)    * HH + 2 * fl);
        u32 ve = *(const u32*)(hb + (size_t)(i1.w & 0xffffu) * HH + 2 * fl);
        u32 vf = *(const u32*)(hb + (size_t)(i1.w >> 16)    * HH + 2 * fl);
        s0 += ((bf2f((u16)(v0 & 0xffffu)) + bf2f((u16)(v1 & 0xffffu)))
             + (bf2f((u16)(v2 & 0xffffu)) + bf2f((u16)(v3 & 0xffffu))))
            + ((bf2f((u16)(v4 & 0xffffu)) + bf2f((u16)(v5 & 0xffffu)))
             + (bf2f((u16)(v6 & 0xffffu)) + bf2f((u16)(v7 & 0xffffu))));
        s0 += ((bf2f((u16)(v8 & 0xffffu)) + bf2f((u16)(v9 & 0xffffu)))
             + (bf2f((u16)(va & 0xffffu)) + bf2f((u16)(vb & 0xffffu))))
            + ((bf2f((u16)(vc & 0xffffu)) + bf2f((u16)(vd & 0xffffu)))
             + (bf2f((u16)(ve & 0xffffu)) + bf2f((u16)(vf & 0xffffu))));
        s1 += ((bf2f((u16)(v0 >> 16)) + bf2f((u16)(v1 >> 16)))
             + (bf2f((u16)(v2 >> 16)) + bf2f((u16)(v3 >> 16))))
            + ((bf2f((u16)(v4 >> 16)) + bf2f((u16)(v5 >> 16)))
             + (bf2f((u16)(v6 >> 16)) + bf2f((u16)(v7 >> 16))));
        s1 += ((bf2f((u16)(v8 >> 16)) + bf2f((u16)(v9 >> 16)))
             + (bf2f((u16)(va >> 16)) + bf2f((u16)(vb >> 16))))
            + ((bf2f((u16)(vc >> 16)) + bf2f((u16)(vd >> 16)))
             + (bf2f((u16)(ve >> 16)) + bf2f((u16)(vf >> 16))));
    }
    if (valid) {
        float inv = 1.0f / (float)max(d, 1);
        u32 p = f2bf(s0 * inv) | (f2bf(s1 * inv) << 16);
        ((u32*)aggb)[(size_t)n * (HH / 2) + fl] = p;
    }
}

// ---------------- Dense per-layer on MFMA; L1 fuses pre-reduced pooling ----------------

__global__ __launch_bounds__(256) void k_dense(
    u16* __restrict__ hb, const u16* __restrict__ aggb,
    const u16* __restrict__ wt,          // layer base in hi plane; lo at +WT_LO
    const float* __restrict__ relb,
    const float* __restrict__ pb1, const float* __restrict__ pb2,
    const int* __restrict__ batch, float* __restrict__ pooled, int do_pool) {
    __shared__ __align__(16) u16 acts[2][64][72];   // 18432 B, 72-pad -> b128 conflict-free
    const int t = threadIdx.x;
    const int w = t >> 6;
    const int l = t & 63;
    const int lr = l & 15, lg = l >> 4;
    const int rowb = w * 16;
    const int nb = blockIdx.x * 64;
    int nodeA = nb + rowb + lr;
    if (nodeA >= NN) nodeA = NN - 1;          // clamped loads; stores guarded

    const u16* w_rel = wt;
    const u16* w_root = wt + 4096;
    const u16* w_p1  = wt + 2 * 4096;
    const u16* w_p2  = wt + 3 * 4096;

    // ---- stage 1: conv = aggb @ rel + relb + hb @ root (no relu) ----
    const u16* agp = aggb + (size_t)nodeA * HH + lg * 8;
    const u16* hbp = hb   + (size_t)nodeA * HH + lg * 8;
    bf16x8 a0 = *(const bf16x8*)agp;
    bf16x8 a1 = *(const bf16x8*)(agp + 32);
    bf16x8 h0 = *(const bf16x8*)hbp;
    bf16x8 h1 = *(const bf16x8*)(hbp + 32);

    f32x4 acc[4];
    #pragma unroll
    for (int tt = 0; tt < 4; ++tt) {
        float b = relb[tt * 16 + lr];
        acc[tt] = (f32x4){b, b, b, b};
    }
    #pragma unroll
    for (int tt = 0; tt < 4; ++tt) {
        const u16* pr = w_rel  + (tt * 16 + lr) * 64 + lg * 8;
        const u16* po = w_root + (tt * 16 + lr) * 64 + lg * 8;
        acc[tt] = __builtin_amdgcn_mfma_f32_16x16x32_bf16(a0, *(const bf16x8*)pr,                acc[tt], 0, 0, 0);
        acc[tt] = __builtin_amdgcn_mfma_f32_16x16x32_bf16(a1, *(const bf16x8*)(pr + 32),         acc[tt], 0, 0, 0);
        acc[tt] = __builtin_amdgcn_mfma_f32_16x16x32_bf16(a0, *(const bf16x8*)(pr + WT_LO),      acc[tt], 0, 0, 0);
        acc[tt] = __builtin_amdgcn_mfma_f32_16x16x32_bf16(a1, *(const bf16x8*)(pr + WT_LO + 32), acc[tt], 0, 0, 0);
        acc[tt] = __builtin_amdgcn_mfma_f32_16x16x32_bf16(h0, *(const bf16x8*)po,                acc[tt], 0, 0, 0);
        acc[tt] = __builtin_amdgcn_mfma_f32_16x16x32_bf16(h1, *(const bf16x8*)(po + 32),         acc[tt], 0, 0, 0);
        acc[tt] = __builtin_amdgcn_mfma_f32_16x16x32_bf16(h0, *(const bf16x8*)(po + WT_LO),      acc[tt], 0, 0, 0);
        acc[tt] = __builtin_amdgcn_mfma_f32_16x16x32_bf16(h1, *(const bf16x8*)(po + WT_LO + 32), acc[tt], 0, 0, 0);
    }
    #pragma unroll
    for (int tt = 0; tt < 4; ++tt)
        #pragma unroll
        for (int r = 0; r < 4; ++r)
            acts[0][rowb + lg * 4 + r][tt * 16 + lr] = (u16)f2bf(acc[tt][r]);
    __syncthreads();

    // ---- stage 2: hidden = relu(conv @ pw1 + pb1) ----
    bf16x8 c0 = *(const bf16x8*)&acts[0][rowb + lr][lg * 8];
    bf16x8 c1 = *(const bf16x8*)&acts[0][rowb + lr][32 + lg * 8];
    f32x4 acc2[4];
    #pragma unroll
    for (int tt = 0; tt < 4; ++tt) {
        float b = pb1[tt * 16 + lr];
        acc2[tt] = (f32x4){b, b, b, b};
    }
    #pragma unroll
    for (int tt = 0; tt < 4; ++tt) {
        const u16* pr = w_p1 + (tt * 16 + lr) * 64 + lg * 8;
        acc2[tt] = __builtin_amdgcn_mfma_f32_16x16x32_bf16(c0, *(const bf16x8*)pr,                acc2[tt], 0, 0, 0);
        acc2[tt] = __builtin_amdgcn_mfma_f32_16x16x32_bf16(c1, *(const bf16x8*)(pr + 32),         acc2[tt], 0, 0, 0);
        acc2[tt] = __builtin_amdgcn_mfma_f32_16x16x32_bf16(c0, *(const bf16x8*)(pr + WT_LO),      acc2[tt], 0, 0, 0);
        acc2[tt] = __builtin_amdgcn_mfma_f32_16x16x32_bf16(c1, *(const bf16x8*)(pr + WT_LO + 32), acc2[tt], 0, 0, 0);
    }
    #pragma unroll
    for (int tt = 0; tt < 4; ++tt)
        #pragma unroll
        for (int r = 0; r < 4; ++r)
            acts[1][rowb + lg * 4 + r][tt * 16 + lr] = (u16)f2bf(fmaxf(acc2[tt][r], 0.0f));
    __syncthreads();

    // ---- stage 3: h = relu(hidden @ pw2 + pb2) ----
    bf16x8 d0 = *(const bf16x8*)&acts[1][rowb + lr][lg * 8];
    bf16x8 d1 = *(const bf16x8*)&acts[1][rowb + lr][32 + lg * 8];
    f32x4 acc3[4];
    #pragma unroll
    for (int tt = 0; tt < 4; ++tt) {
        float b = pb2[tt * 16 + lr];
        acc3[tt] = (f32x4){b, b, b, b};
    }
    #pragma unroll
    for (int tt = 0; tt < 4; ++tt) {
        const u16* pr = w_p2 + (tt * 16 + lr) * 64 + lg * 8;
        acc3[tt] = __builtin_amdgcn_mfma_f32_16x16x32_bf16(d0, *(const bf16x8*)pr,                acc3[tt], 0, 0, 0);
        acc3[tt] = __builtin_amdgcn_mfma_f32_16x16x32_bf16(d1, *(const bf16x8*)(pr + 32),         acc3[tt], 0, 0, 0);
        acc3[tt] = __builtin_amdgcn_mfma_f32_16x16x32_bf16(d0, *(const bf16x8*)(pr + WT_LO),      acc3[tt], 0, 0, 0);
        acc3[tt] = __builtin_amdgcn_mfma_f32_16x16x32_bf16(d1, *(const bf16x8*)(pr + WT_LO + 32), acc3[tt], 0, 0, 0);
    }

    if (!do_pool) {
        #pragma unroll
        for (int tt = 0; tt < 4; ++tt)
            #pragma unroll
            for (int r = 0; r < 4; ++r) {
                int node = nb + rowb + lg * 4 + r;
                if (node < NN)
                    hb[(size_t)node * HH + tt * 16 + lr] = (u16)f2bf(fmaxf(acc3[tt][r], 0.0f));
            }
    } else {
        // fused mean-pool numerator: pre-reduce 64 nodes in LDS, few atomics/feature
        #pragma unroll
        for (int tt = 0; tt < 4; ++tt)
            #pragma unroll
            for (int r = 0; r < 4; ++r)
                acts[0][rowb + lg * 4 + r][tt * 16 + lr] = (u16)f2bf(fmaxf(acc3[tt][r], 0.0f));
        __syncthreads();
        if (t < HH) {
            const int f = t;
            const int n1 = min(64, NN - nb);
            int cur = batch[nb];
            float s = 0.0f;
            for (int i = 0; i < n1; ++i) {
                int g = batch[nb + i];   // sorted; broadcast read
                if (g != cur) {
                    if ((unsigned)cur < NG) atomicAdd(&pooled[cur * HH + f], s);
                    s = 0.0f; cur = g;
                }
                s += bf2f(acts[0][i][f]);
            }
            if ((unsigned)cur < NG) atomicAdd(&pooled[cur * HH + f], s);
        }
    }
}

// ---------------- classifier (pooled sums -> mean -> linear) ----------------

__global__ void k_cls(const float* __restrict__ pooled, const int* __restrict__ batch,
                      const float* __restrict__ w, const float* __restrict__ b,
                      float* __restrict__ out) {
    const int g = blockIdx.x;
    const int t = threadIdx.x;
    if (t >= NCLS) return;
    int lo = 0, hi = NN;
    while (lo < hi) { int mid = (lo + hi) >> 1; if (batch[mid] < g) lo = mid + 1; else hi = mid; }
    const int beg = lo;
    lo = 0; hi = NN;
    while (lo < hi) { int mid = (lo + hi) >> 1; if (batch[mid] < g + 1) lo = mid + 1; else hi = mid; }
    const int cnt = lo - beg;
    const float inv = 1.0f / (float)max(cnt, 1);
    float o = b[t];
    #pragma unroll 8
    for (int k = 0; k < HH; ++k) o += pooled[g * HH + k] * inv * w[k * NCLS + t];
    out[g * NCLS + t] = o;
}

// ---------------- Launch ----------------

extern "C" void kernel_launch(void* const* d_in, const int* in_sizes, int n_in,
                              void* d_out, int out_size, void* d_ws, size_t ws_size,
                              hipStream_t stream) {
    const float* x      = (const float*)d_in[0];
    const int*   ei     = (const int*)d_in[1];    // int32 [2,E]
    const int*   batch  = (const int*)d_in[2];    // int32 [N], sorted
    const float* emb_w1 = (const float*)d_in[3];
    const float* emb_b1 = (const float*)d_in[4];
    const float* emb_w2 = (const float*)d_in[5];
    const float* emb_b2 = (const float*)d_in[6];
    const float* rel_w  = (const float*)d_in[7];
    const float* rel_b  = (const float*)d_in[8];
    const float* root_w = (const float*)d_in[9];
    const float* pw1    = (const float*)d_in[10];
    const float* pb1    = (const float*)d_in[11];
    const float* pw2    = (const float*)d_in[12];
    const float* pb2    = (const float*)d_in[13];
    const float* cls_w  = (const float*)d_in[14];
    const float* cls_b  = (const float*)d_in[15];
    float* out = (float*)d_out;

    // Workspace (~23 MB): hb 6.4 | aggb 6.4 (aliases bedges 5) | slots 8 | wtb 0.18 | misc 1
    char* ws = (char*)d_ws;
    size_t off = 0;
    auto alloc = [&](size_t bytes) -> void* {
        off = (off + 255) & ~(size_t)255;
        void* p = ws + off;
        off += bytes;
        return p;
    };
    u16*   hb     = (u16*)alloc((size_t)(NN + 1) * HH * 2);   // +1 phantom zero row
    u16*   aggb   = (u16*)alloc((size_t)NN * HH * 2);         // bf16 agg
    u32*   bedges = (u32*)aggb;                               // alias: bedges dead before aggb write
    u16*   slots  = (u16*)alloc((size_t)NDP * MAXDEG * 2);
    int*   deg    = (int*)alloc((size_t)NDP * 4);
    int*   gboff  = (int*)alloc((size_t)SBLK * PBUK * 4);
    int*   ghist  = (int*)alloc((size_t)SBLK * PBUK * 4);
    float* pooled = (float*)alloc((size_t)NG * HH * 4);
    u16*   wtb    = (u16*)alloc((size_t)WT_TOT * 2);

    // launch 0: weight transpose + hi/lo split (all 10 matrices)
    k_wprep<<<10, 256, 0, stream>>>(rel_w, root_w, pw1, pw2, emb_w1, emb_w2, wtb);
    // launch 1: psort chunks (first) + embed tiles (MFMA), block-partitioned
    k_embed_psort<<<SBLK + NTILES, 256, 0, stream>>>(
        x, emb_b1, emb_b2, wtb, hb, ei, bedges, gboff, ghist);
    // launch 2: adjacency (+ zero pooled, phantom row, sentinel padding)
    k_adj<<<PBUK, 256, 0, stream>>>(bedges, gboff, ghist, slots, deg, pooled, hb);
    // layer 0 (dense in-place on hb)
    k_agg<<<(NN + 7) / 8, 256, 0, stream>>>(hb, deg, slots, aggb);
    k_dense<<<NTILES, 256, 0, stream>>>(hb, aggb, wtb, rel_b, pb1, pb2, batch, pooled, 0);
    // layer 1 (fused block-pre-reduced pooling; no hb store)
    k_agg<<<(NN + 7) / 8, 256, 0, stream>>>(hb, deg, slots, aggb);
    k_dense<<<NTILES, 256, 0, stream>>>(hb, aggb, wtb + 4 * 4096,
                                        rel_b + HH, pb1 + HH, pb2 + HH,
                                        batch, pooled, 1);
    // classifier
    k_cls<<<NG, 64, 0, stream>>>(pooled, batch, cls_w, cls_b, out);
}